// Round 18
// baseline (487.627 us; speedup 1.0000x reference)
//
#include <hip/hip_runtime.h>
#include <hip/hip_fp16.h>

typedef _Float16 f16;
typedef _Float16 f16x2 __attribute__((ext_vector_type(2)));
typedef _Float16 f16x8 __attribute__((ext_vector_type(8)));
typedef float f32x4 __attribute__((ext_vector_type(4)));

// Combined projection: rows 0..511 = Wq (8 heads x 64), 512..1023 = Wk,
// 1024..1055 = Ww (V), 1056..1311 = Wb (output). Padded to 1408 rows (128-mult).
#define WC_ROWS 1312
#define WC_PAD 1408

// ---------------- prep: combined weight matrix (f16) + bias (f32) ----------------
__global__ void prep_weights(const float* __restrict__ Wq, const float* __restrict__ bq,
                             const float* __restrict__ Wk, const float* __restrict__ bk,
                             const float* __restrict__ Ww, const float* __restrict__ bw,
                             const float* __restrict__ Wb, const float* __restrict__ bb,
                             f16* __restrict__ Wc, float* __restrict__ bias) {
    int id = blockIdx.x * 256 + threadIdx.x;   // WC_PAD*256 threads
    int j = id >> 8, k = id & 255;
    if (j >= WC_PAD) return;
    float v;
    if (j < 512)       v = Wq[j*256 + k];          // Wq flat [8,64,256]: row h*64+d == j
    else if (j < 1024) v = Wk[(j-512)*256 + k];
    else if (j < 1056) v = Ww[(j-1024)*256 + k];
    else if (j < 1312) v = Wb[(j-1056)*256 + k];
    else               v = 0.f;
    Wc[j*256 + k] = (f16)v;
    if (k == 0) {
        float b;
        if (j < 512)       b = bq[j];
        else if (j < 1024) b = bk[j-512];
        else if (j < 1056) b = bw[j-1024];
        else if (j < 1312) b = bb[j-1056];
        else               b = 0.f;
        bias[j] = b;
    }
}

// ---------------- prep: CSR row starts (edges sorted by src; every row non-empty) --
__global__ void build_rows(const int* __restrict__ src, int E, int n, int* __restrict__ rs) {
    int e = blockIdx.x * 256 + threadIdx.x;
    if (e == 0) rs[n] = E;
    if (e < E) {
        if (e == 0 || src[e] != src[e-1]) rs[src[e]] = e;
    }
}

// ---------------- fused projection GEMM: 256x128 tile, reg-staged ------------------
// BM=256 doubles MFMA per K-step per wave (32 vs 16; frag-read ratio 32/12 vs 16/8)
// — r17 tail analysis puts gemm ~85us at only ~425 TF, the biggest tail item.
// Same __syncthreads() reg-staged sync structure as the r6-proven version (raw
// s_barrier staging raced: r10/r12). Per wave: 128x64 output, acc[8][4].
__device__ __forceinline__ int swz_slot(int row, int c) {
    return row * 4 + (c ^ (row & 3) ^ ((row >> 2) & 3));
}

__device__ __forceinline__ uint4 cvt8(float4 a, float4 b) {
    f16x8 o;
    o[0] = (f16)a.x; o[1] = (f16)a.y; o[2] = (f16)a.z; o[3] = (f16)a.w;
    o[4] = (f16)b.x; o[5] = (f16)b.y; o[6] = (f16)b.z; o[7] = (f16)b.w;
    return __builtin_bit_cast(uint4, o);
}

__launch_bounds__(256)
__global__ void gemm_fused(const float* __restrict__ F, const f16* __restrict__ Wc,
                           const float* __restrict__ bias,
                           f16* __restrict__ Qb, f16* __restrict__ Kb, f16* __restrict__ Vb,
                           float* __restrict__ Out, int n) {
    __shared__ uint4 As4[1024];  // 256 rows x 32 k (f16) = 16KB
    __shared__ uint4 Bs4[512];   // 128 rows x 32 k = 8KB
    int t = threadIdx.x;
    int lane = t & 63, w = t >> 6;
    int wm = w >> 1, wn = w & 1;
    long m0 = (long)blockIdx.y * 256;
    int n0 = blockIdx.x * 128;

    f32x4 acc[8][4];
    #pragma unroll
    for (int i = 0; i < 8; i++)
        #pragma unroll
        for (int j = 0; j < 4; j++)
            acc[i][j] = (f32x4){0.f, 0.f, 0.f, 0.f};

    int lrow = t >> 2, lc = t & 3;
    const float4* Fg0 = (const float4*)(F + (m0 + lrow)       * 256 + lc * 8);
    const float4* Fg1 = (const float4*)(F + (m0 + 64  + lrow) * 256 + lc * 8);
    const float4* Fg2 = (const float4*)(F + (m0 + 128 + lrow) * 256 + lc * 8);
    const float4* Fg3 = (const float4*)(F + (m0 + 192 + lrow) * 256 + lc * 8);
    bool ok0 = m0 + lrow < n, ok1 = m0 + 64 + lrow < n;
    bool ok2 = m0 + 128 + lrow < n, ok3 = m0 + 192 + lrow < n;
    const uint4* Bg0 = (const uint4*)(Wc + (long)(n0 + lrow) * 256 + lc * 8);
    const uint4* Bg1 = (const uint4*)(Wc + (long)(n0 + 64 + lrow) * 256 + lc * 8);
    int wsA0 = swz_slot(lrow, lc),       wsA1 = swz_slot(lrow + 64, lc);
    int wsA2 = swz_slot(lrow + 128, lc), wsA3 = swz_slot(lrow + 192, lc);
    int csw = (lane >> 4) ^ (lane & 3) ^ ((lane >> 2) & 3);
    int arow = wm * 128 + (lane & 15);
    int brow = wn * 64 + (lane & 15);

    float4 fa0 = {}, fb0 = {}, fa1 = {}, fb1 = {};
    float4 fa2 = {}, fb2 = {}, fa3 = {}, fb3 = {};
    if (ok0) { fa0 = Fg0[0]; fb0 = Fg0[1]; }
    if (ok1) { fa1 = Fg1[0]; fb1 = Fg1[1]; }
    if (ok2) { fa2 = Fg2[0]; fb2 = Fg2[1]; }
    if (ok3) { fa3 = Fg3[0]; fb3 = Fg3[1]; }
    uint4 rb0 = Bg0[0], rb1 = Bg1[0];
    for (int kt = 0; kt < 8; ++kt) {
        if (kt) __syncthreads();
        As4[wsA0] = cvt8(fa0, fb0);
        As4[wsA1] = cvt8(fa1, fb1);
        As4[wsA2] = cvt8(fa2, fb2);
        As4[wsA3] = cvt8(fa3, fb3);
        Bs4[swz_slot(lrow, lc)] = rb0;
        Bs4[swz_slot(lrow + 64, lc)] = rb1;
        __syncthreads();
        if (kt < 7) {            // prefetch next K-slice (k step 32 f32 = 8 float4)
            if (ok0) { fa0 = Fg0[(kt + 1) * 8]; fb0 = Fg0[(kt + 1) * 8 + 1]; }
            if (ok1) { fa1 = Fg1[(kt + 1) * 8]; fb1 = Fg1[(kt + 1) * 8 + 1]; }
            if (ok2) { fa2 = Fg2[(kt + 1) * 8]; fb2 = Fg2[(kt + 1) * 8 + 1]; }
            if (ok3) { fa3 = Fg3[(kt + 1) * 8]; fb3 = Fg3[(kt + 1) * 8 + 1]; }
            rb0 = Bg0[(kt + 1) * 4];
            rb1 = Bg1[(kt + 1) * 4];
        }
        f16x8 af[8], bf[4];
        const f16x8* Ap = (const f16x8*)As4;
        const f16x8* Bp = (const f16x8*)Bs4;
        #pragma unroll
        for (int i = 0; i < 8; i++) af[i] = Ap[(arow + i * 16) * 4 + csw];
        #pragma unroll
        for (int j = 0; j < 4; j++) bf[j] = Bp[(brow + j * 16) * 4 + csw];
        #pragma unroll
        for (int i = 0; i < 8; i++)
            #pragma unroll
            for (int j = 0; j < 4; j++)
                acc[i][j] = __builtin_amdgcn_mfma_f32_16x16x32_f16(af[i], bf[j], acc[i][j], 0, 0, 0);
    }

    // epilogue: C row = (lane>>4)*4 + reg (M), col = lane&15 (N)  [m89-verified]
    #pragma unroll
    for (int i = 0; i < 8; i++) {
        long gmb = m0 + wm * 128 + i * 16 + (lane >> 4) * 4;
        #pragma unroll
        for (int j = 0; j < 4; j++) {
            int gn = n0 + wn * 64 + j * 16 + (lane & 15);
            float bv = bias[gn];
            #pragma unroll
            for (int r = 0; r < 4; r++) {
                long gm = gmb + r;
                if (gm >= n) continue;
                float v = acc[i][j][r] + bv;
                if (gn < 512)       Qb[gm * 512 + gn] = (f16)v;
                else if (gn < 1024) Kb[gm * 512 + (gn - 512)] = (f16)v;
                else if (gn < 1056) Vb[gm * 32 + (gn - 1024)] = (f16)v;
                else if (gn < 1312) Out[gm * 256 + (gn - 1056)] = v;
                // gn in [1312,1408): padding, no write
            }
        }
    }
}

// ---------------- f16x2 dot helper ----------------
__device__ __forceinline__ float fd2(unsigned a, unsigned b, float c) {
#if defined(__has_builtin)
#if __has_builtin(__builtin_amdgcn_fdot2)
    return __builtin_amdgcn_fdot2(__builtin_bit_cast(f16x2, a), __builtin_bit_cast(f16x2, b), c, false);
#else
    f16x2 x = __builtin_bit_cast(f16x2, a), y = __builtin_bit_cast(f16x2, b);
    return c + (float)x[0] * (float)y[0] + (float)x[1] * (float)y[1];
#endif
#else
    f16x2 x = __builtin_bit_cast(f16x2, a), y = __builtin_bit_cast(f16x2, b);
    return c + (float)x[0] * (float)y[0] + (float)x[1] * (float)y[1];
#endif
}

// ---------------- phase A v6: chunk-lane coalesced, 8 edges/thread, packed reduce --
// r16 structure (lanes j=0..7 read one 128B K line in ONE instruction; h = bid&7
// head-phasing; packed f16x2 group reduce) with 8 edges/thread: 8 K-line gathers
// issued back-to-back and PINNED co-resident (asm) -> 2x misses in flight per
// wave vs r16's 4, wave count halved. Targets the remaining gap to the ~2.27TB/s
// miss wall (r16: 2.04).
__launch_bounds__(256)
__global__ void edge_scores(const int* __restrict__ srcA, const int* __restrict__ dstA,
                            const f16* __restrict__ Qb, const f16* __restrict__ Kb,
                            f16* __restrict__ sE, int E, int Epad) {
    int bid = blockIdx.x;
    int h = bid & 7;                          // head = XCD (round-robin dispatch)
    int j = threadIdx.x & 7;                  // 16B chunk within the head's 128B line
    int g = threadIdx.x >> 3;                 // edge group 0..31
    int e0 = (bid >> 3) * 256 + g;            // edges e0 + 32*u, u=0..7
    int s[8], d[8];
    #pragma unroll
    for (int u = 0; u < 8; u++) {
        int e = e0 + 32 * u;
        bool ok = e < E;
        s[u] = ok ? srcA[e] : 0;
        d[u] = ok ? dstA[e] : 0;
    }
    uint4 kv[8], qv[8];
    #pragma unroll
    for (int u = 0; u < 8; u++)               // 8 gather lines issued back-to-back
        kv[u] = *(const uint4*)(Kb + (size_t)d[u] * 512 + h * 64 + j * 8);
    #pragma unroll
    for (int u = 0; u < 8; u++)               // pin: all 8 co-resident, one waitcnt
        asm volatile("" : "+v"(kv[u].x), "+v"(kv[u].y), "+v"(kv[u].z), "+v"(kv[u].w));
    #pragma unroll
    for (int u = 0; u < 8; u++)               // 8 Q chunks (L1/L2-hot)
        qv[u] = *(const uint4*)(Qb + (size_t)s[u] * 512 + h * 64 + j * 8);
    float aa[8];
    #pragma unroll
    for (int u = 0; u < 8; u++) {
        float a = 0.f;
        a = fd2(qv[u].x, kv[u].x, a);
        a = fd2(qv[u].y, kv[u].y, a);
        a = fd2(qv[u].z, kv[u].z, a);
        a = fd2(qv[u].w, kv[u].w, a);
        aa[u] = a;
    }
    // packed 8-lane-group reduction: 4 regs carry 8 edges' partials
    unsigned uu[4];
    #pragma unroll
    for (int p = 0; p < 4; p++) {
        f16x2 pv;
        pv[0] = (f16)aa[2*p];
        pv[1] = (f16)aa[2*p + 1];
        uu[p] = __builtin_bit_cast(unsigned, pv);
    }
    #pragma unroll
    for (int off = 1; off < 8; off <<= 1) {
        #pragma unroll
        for (int p = 0; p < 4; p++) {
            unsigned vv = __shfl_xor(uu[p], off);
            f16x2 r = __builtin_bit_cast(f16x2, uu[p]) + __builtin_bit_cast(f16x2, vv);
            uu[p] = __builtin_bit_cast(unsigned, r);
        }
    }
    if (j == 0) {
        size_t bo = (size_t)h * Epad;
        #pragma unroll
        for (int p = 0; p < 4; p++) {
            f16x2 r = __builtin_bit_cast(f16x2, uu[p]);
            int ea = e0 + 32 * (2*p), eb = e0 + 32 * (2*p + 1);
            if (ea < E) sE[bo + ea] = r[0];
            if (eb < E) sE[bo + eb] = r[1];
        }
    }
}

// ---------------- transpose: sE [h][Epad] -> sT [e][8] -----------------------------
// Scores wants [h][Epad] (coalesced head-phased stores); agg wants [e][8] (one
// f16x8 per lane per tile). Register 8x8 transpose; sT aliases dead Qb.
__launch_bounds__(256)
__global__ void transpose_sE(const f16* __restrict__ sE, f16* __restrict__ sT,
                             int E, int Epad) {
    long e8 = (long)blockIdx.x * 2048 + (long)threadIdx.x * 8;   // this thread's 8 edges
    if (e8 >= E) return;
    f16x8 rowv[8];
    #pragma unroll
    for (int h = 0; h < 8; h++)
        rowv[h] = *(const f16x8*)(sE + (size_t)h * Epad + e8);   // 8 edges of head h
    #pragma unroll
    for (int u = 0; u < 8; u++) {
        long e = e8 + u;
        if (e < E) {
            f16x8 o;
            #pragma unroll
            for (int h = 0; h < 8; h++) o[h] = rowv[h][u];
            *(f16x8*)(sT + (size_t)e * 8) = o;
        }
    }
}

// ---------------- phase B v3: single-pass online softmax, [e][8] sE (r17-proven) ---
__launch_bounds__(256)
__global__ void edge_agg(const int* __restrict__ rs, const int* __restrict__ dstA,
                         const f16* __restrict__ sT, const f16* __restrict__ Vb,
                         float* __restrict__ Out, int n) {
    __shared__ __align__(16) f16 P_lds[4][16][64];
    __shared__ int dS[4][64];
    int w = threadIdx.x >> 6, lane = threadIdx.x & 63;
    int row = blockIdx.x * 4 + w;
    if (row >= n) return;
    int e0 = rs[row], deg = rs[row + 1] - e0;
    {   // zero A-frag rows 8..15 (read by MFMA, results discarded; avoid NaN garbage)
        f16x8 z = {};
        *(f16x8*)&P_lds[w][8 + (lane >> 3)][(lane & 7) * 8] = z;
    }
    asm volatile("" ::: "memory");
    float m[8];
    #pragma unroll
    for (int h = 0; h < 8; h++) m[h] = -1e30f;
    f32x4 acc0 = {}, acc1 = {}, accl = {};
    int ec0 = (lane >> 4) * 8, h_a = lane & 15, hsel = (lane >> 4) & 1;
    f16x8 ones;
    #pragma unroll
    for (int j = 0; j < 8; j++) ones[j] = (f16)1.f;

    for (int base = 0; base < deg; base += 64) {
        int nE = deg - base; if (nE > 64) nE = 64;
        bool act = lane < nE;
        int ee = e0 + base + (act ? lane : 0);
        dS[w][lane] = dstA[ee];
        f16x8 s8 = *(const f16x8*)(sT + (size_t)ee * 8);   // all 8 heads, one load
        float sc[8];
        #pragma unroll
        for (int h = 0; h < 8; h++) {
            float sv = act ? (float)s8[h] : -1e30f;
            float tv = sv;
            #pragma unroll
            for (int off = 1; off < 64; off <<= 1) tv = fmaxf(tv, __shfl_xor(tv, off));
            float nm = fmaxf(m[h], tv);
            sc[h] = __expf(m[h] - nm);
            float p = act ? __expf(sv - nm) : 0.f;
            P_lds[w][h][lane ^ (h << 3)] = (f16)p;
            m[h] = nm;
        }
        #pragma unroll
        for (int r = 0; r < 4; r++) {   // rescale accs (head = hsel*4 + r)
            float f = hsel ? sc[r + 4] : sc[r];
            acc0[r] *= f;
            acc1[r] *= f;
            accl[r] *= f;
        }
        asm volatile("" ::: "memory");   // LDS writes ordered before the punned reads
        // A-frags: P[h][k], k = ks*32 + ec0 + j (XOR-decoded contiguous b128)
        f16x8 a0 = *(const f16x8*)&P_lds[w][h_a][(ec0)      ^ ((h_a & 7) << 3)];
        f16x8 a1 = *(const f16x8*)&P_lds[w][h_a][(32 + ec0) ^ ((h_a & 7) << 3)];
        // B-frags: V[e][dim], dim = nh*16 + (lane&15)
        f16x8 bf0a, bf0b, bf1a, bf1b;
        #pragma unroll
        for (int j = 0; j < 8; j++) {
            int dd0 = dS[w][ec0 + j];
            int dd1 = dS[w][32 + ec0 + j];
            const f16* vp0 = Vb + (size_t)dd0 * 32 + (lane & 15);
            const f16* vp1 = Vb + (size_t)dd1 * 32 + (lane & 15);
            bf0a[j] = vp0[0];  bf0b[j] = vp0[16];
            bf1a[j] = vp1[0];  bf1b[j] = vp1[16];
        }
        asm volatile("" ::: "memory");   // reads complete before next tile's writes
        acc0 = __builtin_amdgcn_mfma_f32_16x16x32_f16(a0, bf0a, acc0, 0, 0, 0);
        acc0 = __builtin_amdgcn_mfma_f32_16x16x32_f16(a1, bf1a, acc0, 0, 0, 0);
        acc1 = __builtin_amdgcn_mfma_f32_16x16x32_f16(a0, bf0b, acc1, 0, 0, 0);
        acc1 = __builtin_amdgcn_mfma_f32_16x16x32_f16(a1, bf1b, acc1, 0, 0, 0);
        accl = __builtin_amdgcn_mfma_f32_16x16x32_f16(a0, ones, accl, 0, 0, 0);
        accl = __builtin_amdgcn_mfma_f32_16x16x32_f16(a1, ones, accl, 0, 0, 0);
    }
    // epilogue: D row = hsel*4 + r = head, col = lane&15; out dim = h*32 + nh*16 + col
    if (lane < 32) {
        float* op = Out + (size_t)row * 256 + (lane & 15);
        #pragma unroll
        for (int r = 0; r < 4; r++) {
            int h = hsel * 4 + r;
            float inv = 1.f / accl[r];
            op[h * 32]      += acc0[r] * inv;
            op[h * 32 + 16] += acc1[r] * inv;
        }
    }
}

// ---------------- launch ----------------
extern "C" void kernel_launch(void* const* d_in, const int* in_sizes, int n_in,
                              void* d_out, int out_size, void* d_ws, size_t ws_size,
                              hipStream_t stream) {
    const float* F  = (const float*)d_in[0];
    const int*   ei = (const int*)d_in[1];
    const float* Wq = (const float*)d_in[2];
    const float* bq = (const float*)d_in[3];
    const float* Wk = (const float*)d_in[4];
    const float* bk = (const float*)d_in[5];
    const float* Ww = (const float*)d_in[6];
    const float* bw = (const float*)d_in[7];
    const float* Wb = (const float*)d_in[8];
    const float* bb = (const float*)d_in[9];
    int n = in_sizes[0] / 256;       // 50000
    int E = in_sizes[1] / 2;
    const int* srcA = ei;
    const int* dstA = ei + E;
    int n_pad = (n + 255) & ~255;    // 256-row GEMM tiles
    int Epad = (E + 63) & ~63;

    // workspace carve-out (~133 MB); sT aliases Qb (dead after edge_scores)
    char* wp = (char*)d_ws;
    auto alloc = [&](size_t bytes) { void* p = wp; wp += (bytes + 255) & ~255ull; return p; };
    f16*   sE   = (f16*)alloc((size_t)Epad * 8 * 2);
    f16*   Wc   = (f16*)alloc((size_t)WC_PAD * 256 * 2);
    float* bias = (float*)alloc((size_t)WC_PAD * 4);
    f16*   Qb   = (f16*)alloc((size_t)n * 512 * 2);
    f16*   Kb   = (f16*)alloc((size_t)n * 512 * 2);
    f16*   Vb   = (f16*)alloc((size_t)n * 32 * 2);
    int*   rs   = (int*)alloc((size_t)(n + 1) * 4);
    float* Out  = (float*)d_out;
    f16*   sT   = Qb;                // alias: Qb (51MB) >= sT (26MB), dead after scores

    prep_weights<<<WC_PAD, 256, 0, stream>>>(Wq, bq, Wk, bk, Ww, bw, Wb, bb, Wc, bias);
    build_rows<<<(E + 255) / 256, 256, 0, stream>>>(srcA, E, n, rs);
    dim3 g(WC_PAD / 128, n_pad / 256);   // N fastest: A-panel L2-reuse, B L2-resident
    gemm_fused<<<g, 256, 0, stream>>>(F, Wc, bias, Qb, Kb, Vb, Out, n);
    int wgph = (E + 255) / 256;          // 256 edges per block per head
    edge_scores<<<8 * wgph, 256, 0, stream>>>(srcA, dstA, Qb, Kb, sE, E, Epad);
    transpose_sE<<<(int)((E + 2047) / 2048), 256, 0, stream>>>(sE, sT, E, Epad);
    edge_agg<<<(n + 3) / 4, 256, 0, stream>>>(rs, dstA, sT, Vb, Out, n);
}

// Round 19
// 425.817 us; speedup vs baseline: 1.1452x; 1.1452x over previous
//
#include <hip/hip_runtime.h>
#include <hip/hip_fp16.h>

typedef _Float16 f16;
typedef _Float16 f16x2 __attribute__((ext_vector_type(2)));
typedef _Float16 f16x8 __attribute__((ext_vector_type(8)));
typedef float f32x4 __attribute__((ext_vector_type(4)));

// Combined projection: rows 0..511 = Wq (8 heads x 64), 512..1023 = Wk,
// 1024..1055 = Ww (V), 1056..1311 = Wb (output). Padded to 1408 rows (128-mult).
#define WC_ROWS 1312
#define WC_PAD 1408

// ---------------- prep: combined weight matrix (f16) + bias (f32) ----------------
__global__ void prep_weights(const float* __restrict__ Wq, const float* __restrict__ bq,
                             const float* __restrict__ Wk, const float* __restrict__ bk,
                             const float* __restrict__ Ww, const float* __restrict__ bw,
                             const float* __restrict__ Wb, const float* __restrict__ bb,
                             f16* __restrict__ Wc, float* __restrict__ bias) {
    int id = blockIdx.x * 256 + threadIdx.x;   // WC_PAD*256 threads
    int j = id >> 8, k = id & 255;
    if (j >= WC_PAD) return;
    float v;
    if (j < 512)       v = Wq[j*256 + k];          // Wq flat [8,64,256]: row h*64+d == j
    else if (j < 1024) v = Wk[(j-512)*256 + k];
    else if (j < 1056) v = Ww[(j-1024)*256 + k];
    else if (j < 1312) v = Wb[(j-1056)*256 + k];
    else               v = 0.f;
    Wc[j*256 + k] = (f16)v;
    if (k == 0) {
        float b;
        if (j < 512)       b = bq[j];
        else if (j < 1024) b = bk[j-512];
        else if (j < 1056) b = bw[j-1024];
        else if (j < 1312) b = bb[j-1056];
        else               b = 0.f;
        bias[j] = b;
    }
}

// ---------------- prep: CSR row starts (edges sorted by src; every row non-empty) --
__global__ void build_rows(const int* __restrict__ src, int E, int n, int* __restrict__ rs) {
    int e = blockIdx.x * 256 + threadIdx.x;
    if (e == 0) rs[n] = E;
    if (e < E) {
        if (e == 0 || src[e] != src[e-1]) rs[src[e]] = e;
    }
}

// ---------------- fused projection GEMM (r6/r17-proven 128x128 reg-staged) ---------
// REVERTED from r18's 256x128: acc[8][4] (~128 acc VGPRs) dropped occupancy to
// ~1-2 waves/SIMD in this barrier-synced shallow-K loop -> tail +28us. The 128x128
// 4-wave version with __syncthreads() staging is the measured optimum here
// (raw s_barrier staging raced: r10/r12).
__device__ __forceinline__ int swz_slot(int row, int c) {
    return row * 4 + (c ^ (row & 3) ^ ((row >> 2) & 3));
}

__device__ __forceinline__ uint4 cvt8(float4 a, float4 b) {
    f16x8 o;
    o[0] = (f16)a.x; o[1] = (f16)a.y; o[2] = (f16)a.z; o[3] = (f16)a.w;
    o[4] = (f16)b.x; o[5] = (f16)b.y; o[6] = (f16)b.z; o[7] = (f16)b.w;
    return __builtin_bit_cast(uint4, o);
}

__launch_bounds__(256)
__global__ void gemm_fused(const float* __restrict__ F, const f16* __restrict__ Wc,
                           const float* __restrict__ bias,
                           f16* __restrict__ Qb, f16* __restrict__ Kb, f16* __restrict__ Vb,
                           float* __restrict__ Out, int n) {
    __shared__ uint4 As4[512];   // 128 rows x 32 k (f16) = 8KB
    __shared__ uint4 Bs4[512];   // 128 rows x 32 k = 8KB
    int t = threadIdx.x;
    int lane = t & 63, w = t >> 6;
    int wm = w >> 1, wn = w & 1;
    long m0 = (long)blockIdx.y * 128;
    int n0 = blockIdx.x * 128;

    f32x4 acc[4][4];
    #pragma unroll
    for (int i = 0; i < 4; i++)
        #pragma unroll
        for (int j = 0; j < 4; j++)
            acc[i][j] = (f32x4){0.f, 0.f, 0.f, 0.f};

    int lrow = t >> 2, lc = t & 3;
    long row0 = m0 + lrow, row1 = m0 + 64 + lrow;
    const float4* Fg0 = (const float4*)(F + row0 * 256 + lc * 8);   // 8 f32 per thread
    const float4* Fg1 = (const float4*)(F + row1 * 256 + lc * 8);
    const uint4*  Bg0 = (const uint4*)(Wc + (long)(n0 + lrow) * 256 + lc * 8);
    const uint4*  Bg1 = (const uint4*)(Wc + (long)(n0 + 64 + lrow) * 256 + lc * 8);
    bool ok0 = row0 < n, ok1 = row1 < n;
    int ws0 = swz_slot(lrow, lc);
    int ws1 = swz_slot(lrow + 64, lc);
    int csw = (lane >> 4) ^ (lane & 3) ^ ((lane >> 2) & 3);
    int arow = wm * 64 + (lane & 15);
    int brow = wn * 64 + (lane & 15);

    float4 fa0 = {}, fb0 = {}, fa1 = {}, fb1 = {};
    if (ok0) { fa0 = Fg0[0]; fb0 = Fg0[1]; }
    if (ok1) { fa1 = Fg1[0]; fb1 = Fg1[1]; }
    uint4 rb0 = Bg0[0], rb1 = Bg1[0];
    for (int kt = 0; kt < 8; ++kt) {
        if (kt) __syncthreads();
        As4[ws0] = cvt8(fa0, fb0);
        As4[ws1] = cvt8(fa1, fb1);
        Bs4[ws0] = rb0;
        Bs4[ws1] = rb1;
        __syncthreads();
        if (kt < 7) {            // prefetch next K-slice (k step 32 f32 = 8 float4)
            if (ok0) { fa0 = Fg0[(kt + 1) * 8]; fb0 = Fg0[(kt + 1) * 8 + 1]; }
            if (ok1) { fa1 = Fg1[(kt + 1) * 8]; fb1 = Fg1[(kt + 1) * 8 + 1]; }
            rb0 = Bg0[(kt + 1) * 4];
            rb1 = Bg1[(kt + 1) * 4];
        }
        f16x8 af[4], bf[4];
        const f16x8* Ap = (const f16x8*)As4;
        const f16x8* Bp = (const f16x8*)Bs4;
        #pragma unroll
        for (int i = 0; i < 4; i++) af[i] = Ap[(arow + i * 16) * 4 + csw];
        #pragma unroll
        for (int j = 0; j < 4; j++) bf[j] = Bp[(brow + j * 16) * 4 + csw];
        #pragma unroll
        for (int i = 0; i < 4; i++)
            #pragma unroll
            for (int j = 0; j < 4; j++)
                acc[i][j] = __builtin_amdgcn_mfma_f32_16x16x32_f16(af[i], bf[j], acc[i][j], 0, 0, 0);
    }

    // epilogue: C row = (lane>>4)*4 + reg (M), col = lane&15 (N)  [m89-verified]
    #pragma unroll
    for (int i = 0; i < 4; i++) {
        long gmb = m0 + wm * 64 + i * 16 + (lane >> 4) * 4;
        #pragma unroll
        for (int j = 0; j < 4; j++) {
            int gn = n0 + wn * 64 + j * 16 + (lane & 15);
            float bv = bias[gn];
            #pragma unroll
            for (int r = 0; r < 4; r++) {
                long gm = gmb + r;
                if (gm >= n) continue;
                float v = acc[i][j][r] + bv;
                if (gn < 512)       Qb[gm * 512 + gn] = (f16)v;
                else if (gn < 1024) Kb[gm * 512 + (gn - 512)] = (f16)v;
                else if (gn < 1056) Vb[gm * 32 + (gn - 1024)] = (f16)v;
                else if (gn < 1312) Out[gm * 256 + (gn - 1056)] = v;
                // gn in [1312,1408): padding, no write
            }
        }
    }
}

// ---------------- f16x2 dot helper ----------------
__device__ __forceinline__ float fd2(unsigned a, unsigned b, float c) {
#if defined(__has_builtin)
#if __has_builtin(__builtin_amdgcn_fdot2)
    return __builtin_amdgcn_fdot2(__builtin_bit_cast(f16x2, a), __builtin_bit_cast(f16x2, b), c, false);
#else
    f16x2 x = __builtin_bit_cast(f16x2, a), y = __builtin_bit_cast(f16x2, b);
    return c + (float)x[0] * (float)y[0] + (float)x[1] * (float)y[1];
#endif
#else
    f16x2 x = __builtin_bit_cast(f16x2, a), y = __builtin_bit_cast(f16x2, b);
    return c + (float)x[0] * (float)y[0] + (float)x[1] * (float)y[1];
#endif
}

// ---------------- phase A v5 (r16/r17-proven): chunk-lane coalesced, 4 edges/thread
// REVERTED from r18's 8-edge + pin (266us: pin forced full-batch wait, occupancy
// 87->78%). Lanes j=0..7 read one 128B K line in ONE instruction; 4 edges/thread;
// h = bid&7 head-phasing (per-XCD K working set 6.4MB); packed f16x2 group reduce.
// 236us @ ~90% of the measured miss wall — the local optimum (pin refuted 2x).
__launch_bounds__(256)
__global__ void edge_scores(const int* __restrict__ srcA, const int* __restrict__ dstA,
                            const f16* __restrict__ Qb, const f16* __restrict__ Kb,
                            f16* __restrict__ sE, int E, int Epad) {
    int bid = blockIdx.x;
    int h = bid & 7;                          // head = XCD (round-robin dispatch)
    int j = threadIdx.x & 7;                  // 16B chunk within the head's 128B line
    int g = threadIdx.x >> 3;                 // edge group 0..31
    int e0 = (bid >> 3) * 128 + g;            // edges e0 + 32*u, u=0..3
    int s[4], d[4];
    #pragma unroll
    for (int u = 0; u < 4; u++) {
        int e = e0 + 32 * u;
        bool ok = e < E;
        s[u] = ok ? srcA[e] : 0;
        d[u] = ok ? dstA[e] : 0;
    }
    uint4 kv[4], qv[4];
    #pragma unroll
    for (int u = 0; u < 4; u++)               // 4 gather lines issued back-to-back
        kv[u] = *(const uint4*)(Kb + (size_t)d[u] * 512 + h * 64 + j * 8);
    #pragma unroll
    for (int u = 0; u < 4; u++)               // 4 Q chunks (L1/L2-hot)
        qv[u] = *(const uint4*)(Qb + (size_t)s[u] * 512 + h * 64 + j * 8);
    float aa[4];
    #pragma unroll
    for (int u = 0; u < 4; u++) {
        float a = 0.f;
        a = fd2(qv[u].x, kv[u].x, a);
        a = fd2(qv[u].y, kv[u].y, a);
        a = fd2(qv[u].z, kv[u].z, a);
        a = fd2(qv[u].w, kv[u].w, a);
        aa[u] = a;
    }
    // packed 8-lane-group reduction: 2 regs carry 4 edges' partials
    f16x2 p01, p23;
    p01[0] = (f16)aa[0]; p01[1] = (f16)aa[1];
    p23[0] = (f16)aa[2]; p23[1] = (f16)aa[3];
    unsigned u01 = __builtin_bit_cast(unsigned, p01);
    unsigned u23 = __builtin_bit_cast(unsigned, p23);
    #pragma unroll
    for (int off = 1; off < 8; off <<= 1) {
        unsigned v01 = __shfl_xor(u01, off);
        unsigned v23 = __shfl_xor(u23, off);
        f16x2 r01 = __builtin_bit_cast(f16x2, u01) + __builtin_bit_cast(f16x2, v01);
        f16x2 r23 = __builtin_bit_cast(f16x2, u23) + __builtin_bit_cast(f16x2, v23);
        u01 = __builtin_bit_cast(unsigned, r01);
        u23 = __builtin_bit_cast(unsigned, r23);
    }
    if (j == 0) {
        f16x2 r01 = __builtin_bit_cast(f16x2, u01);
        f16x2 r23 = __builtin_bit_cast(f16x2, u23);
        size_t bo = (size_t)h * Epad;
        if (e0 < E)      sE[bo + e0]      = r01[0];
        if (e0+32 < E)   sE[bo + e0+32]   = r01[1];
        if (e0+64 < E)   sE[bo + e0+64]   = r23[0];
        if (e0+96 < E)   sE[bo + e0+96]   = r23[1];
    }
}

// ---------------- transpose: sE [h][Epad] -> sT [e][8] -----------------------------
// Scores wants [h][Epad] (coalesced head-phased stores); agg wants [e][8] (one
// f16x8 per lane per tile). Register 8x8 transpose; sT aliases dead Qb.
__launch_bounds__(256)
__global__ void transpose_sE(const f16* __restrict__ sE, f16* __restrict__ sT,
                             int E, int Epad) {
    long e8 = (long)blockIdx.x * 2048 + (long)threadIdx.x * 8;   // this thread's 8 edges
    if (e8 >= E) return;
    f16x8 rowv[8];
    #pragma unroll
    for (int h = 0; h < 8; h++)
        rowv[h] = *(const f16x8*)(sE + (size_t)h * Epad + e8);   // 8 edges of head h
    #pragma unroll
    for (int u = 0; u < 8; u++) {
        long e = e8 + u;
        if (e < E) {
            f16x8 o;
            #pragma unroll
            for (int h = 0; h < 8; h++) o[h] = rowv[h][u];
            *(f16x8*)(sT + (size_t)e * 8) = o;
        }
    }
}

// ---------------- phase B v4: single-pass online softmax, packed f16x2 max reduce --
// r17-proven structure; the per-tile per-head max butterflies (48 shfl + 48 fmax)
// are packed into 4x f16x2 regs reduced with v_pk_max_f16 (24 shfl + 24 pk_max).
// f16 max is exact -> numerically identical max path.
__launch_bounds__(256)
__global__ void edge_agg(const int* __restrict__ rs, const int* __restrict__ dstA,
                         const f16* __restrict__ sT, const f16* __restrict__ Vb,
                         float* __restrict__ Out, int n) {
    __shared__ __align__(16) f16 P_lds[4][16][64];
    __shared__ int dS[4][64];
    int w = threadIdx.x >> 6, lane = threadIdx.x & 63;
    int row = blockIdx.x * 4 + w;
    if (row >= n) return;
    int e0 = rs[row], deg = rs[row + 1] - e0;
    {   // zero A-frag rows 8..15 (read by MFMA, results discarded; avoid NaN garbage)
        f16x8 z = {};
        *(f16x8*)&P_lds[w][8 + (lane >> 3)][(lane & 7) * 8] = z;
    }
    asm volatile("" ::: "memory");
    float m[8];
    #pragma unroll
    for (int h = 0; h < 8; h++) m[h] = -1e30f;
    f32x4 acc0 = {}, acc1 = {}, accl = {};
    int ec0 = (lane >> 4) * 8, h_a = lane & 15, hsel = (lane >> 4) & 1;
    f16x8 ones;
    #pragma unroll
    for (int j = 0; j < 8; j++) ones[j] = (f16)1.f;

    for (int base = 0; base < deg; base += 64) {
        int nE = deg - base; if (nE > 64) nE = 64;
        bool act = lane < nE;
        int ee = e0 + base + (act ? lane : 0);
        dS[w][lane] = dstA[ee];
        f16x8 s8 = *(const f16x8*)(sT + (size_t)ee * 8);   // all 8 heads, one load
        // packed tile-max: 4x f16x2 butterflies (f16 max is exact)
        f16x2 mx[4];
        #pragma unroll
        for (int p = 0; p < 4; p++) {
            f16x2 v;
            v[0] = s8[2*p]; v[1] = s8[2*p + 1];
            if (!act) { v[0] = (f16)(-65504.f); v[1] = (f16)(-65504.f); }
            mx[p] = v;
        }
        #pragma unroll
        for (int off = 1; off < 64; off <<= 1) {
            #pragma unroll
            for (int p = 0; p < 4; p++) {
                unsigned o = __shfl_xor(__builtin_bit_cast(unsigned, mx[p]), off);
                mx[p] = __builtin_elementwise_max(mx[p], __builtin_bit_cast(f16x2, o));
            }
        }
        float sc[8];
        #pragma unroll
        for (int h = 0; h < 8; h++) {
            float tv = (float)mx[h >> 1][h & 1];
            float nm = fmaxf(m[h], tv);
            sc[h] = __expf(m[h] - nm);
            float sv = act ? (float)s8[h] : -1e30f;
            float p = act ? __expf(sv - nm) : 0.f;
            P_lds[w][h][lane ^ (h << 3)] = (f16)p;
            m[h] = nm;
        }
        #pragma unroll
        for (int r = 0; r < 4; r++) {   // rescale accs (head = hsel*4 + r)
            float f = hsel ? sc[r + 4] : sc[r];
            acc0[r] *= f;
            acc1[r] *= f;
            accl[r] *= f;
        }
        asm volatile("" ::: "memory");   // LDS writes ordered before the punned reads
        // A-frags: P[h][k], k = ks*32 + ec0 + j (XOR-decoded contiguous b128)
        f16x8 a0 = *(const f16x8*)&P_lds[w][h_a][(ec0)      ^ ((h_a & 7) << 3)];
        f16x8 a1 = *(const f16x8*)&P_lds[w][h_a][(32 + ec0) ^ ((h_a & 7) << 3)];
        // B-frags: V[e][dim], dim = nh*16 + (lane&15)
        f16x8 bf0a, bf0b, bf1a, bf1b;
        #pragma unroll
        for (int j = 0; j < 8; j++) {
            int dd0 = dS[w][ec0 + j];
            int dd1 = dS[w][32 + ec0 + j];
            const f16* vp0 = Vb + (size_t)dd0 * 32 + (lane & 15);
            const f16* vp1 = Vb + (size_t)dd1 * 32 + (lane & 15);
            bf0a[j] = vp0[0];  bf0b[j] = vp0[16];
            bf1a[j] = vp1[0];  bf1b[j] = vp1[16];
        }
        asm volatile("" ::: "memory");   // reads complete before next tile's writes
        acc0 = __builtin_amdgcn_mfma_f32_16x16x32_f16(a0, bf0a, acc0, 0, 0, 0);
        acc0 = __builtin_amdgcn_mfma_f32_16x16x32_f16(a1, bf1a, acc0, 0, 0, 0);
        acc1 = __builtin_amdgcn_mfma_f32_16x16x32_f16(a0, bf0b, acc1, 0, 0, 0);
        acc1 = __builtin_amdgcn_mfma_f32_16x16x32_f16(a1, bf1b, acc1, 0, 0, 0);
        accl = __builtin_amdgcn_mfma_f32_16x16x32_f16(a0, ones, accl, 0, 0, 0);
        accl = __builtin_amdgcn_mfma_f32_16x16x32_f16(a1, ones, accl, 0, 0, 0);
    }
    // epilogue: D row = hsel*4 + r = head, col = lane&15; out dim = h*32 + nh*16 + col
    if (lane < 32) {
        float* op = Out + (size_t)row * 256 + (lane & 15);
        #pragma unroll
        for (int r = 0; r < 4; r++) {
            int h = hsel * 4 + r;
            float inv = 1.f / accl[r];
            op[h * 32]      += acc0[r] * inv;
            op[h * 32 + 16] += acc1[r] * inv;
        }
    }
}

// ---------------- launch ----------------
extern "C" void kernel_launch(void* const* d_in, const int* in_sizes, int n_in,
                              void* d_out, int out_size, void* d_ws, size_t ws_size,
                              hipStream_t stream) {
    const float* F  = (const float*)d_in[0];
    const int*   ei = (const int*)d_in[1];
    const float* Wq = (const float*)d_in[2];
    const float* bq = (const float*)d_in[3];
    const float* Wk = (const float*)d_in[4];
    const float* bk = (const float*)d_in[5];
    const float* Ww = (const float*)d_in[6];
    const float* bw = (const float*)d_in[7];
    const float* Wb = (const float*)d_in[8];
    const float* bb = (const float*)d_in[9];
    int n = in_sizes[0] / 256;       // 50000
    int E = in_sizes[1] / 2;
    const int* srcA = ei;
    const int* dstA = ei + E;
    int n_pad = (n + 127) & ~127;
    int Epad = (E + 63) & ~63;

    // workspace carve-out (~133 MB); sT aliases Qb (dead after edge_scores)
    char* wp = (char*)d_ws;
    auto alloc = [&](size_t bytes) { void* p = wp; wp += (bytes + 255) & ~255ull; return p; };
    f16*   sE   = (f16*)alloc((size_t)Epad * 8 * 2);
    f16*   Wc   = (f16*)alloc((size_t)WC_PAD * 256 * 2);
    float* bias = (float*)alloc((size_t)WC_PAD * 4);
    f16*   Qb   = (f16*)alloc((size_t)n * 512 * 2);
    f16*   Kb   = (f16*)alloc((size_t)n * 512 * 2);
    f16*   Vb   = (f16*)alloc((size_t)n * 32 * 2);
    int*   rs   = (int*)alloc((size_t)(n + 1) * 4);
    float* Out  = (float*)d_out;
    f16*   sT   = Qb;                // alias: Qb (51MB) >= sT (26MB), dead after scores

    prep_weights<<<WC_PAD, 256, 0, stream>>>(Wq, bq, Wk, bk, Ww, bw, Wb, bb, Wc, bias);
    build_rows<<<(E + 255) / 256, 256, 0, stream>>>(srcA, E, n, rs);
    dim3 g(WC_PAD / 128, n_pad / 128);   // N fastest: A-panel L2-reuse, B L2-resident
    gemm_fused<<<g, 256, 0, stream>>>(F, Wc, bias, Qb, Kb, Vb, Out, n);
    int wgph = (E + 127) / 128;          // 128 edges per block per head
    edge_scores<<<8 * wgph, 256, 0, stream>>>(srcA, dstA, Qb, Kb, sE, E, Epad);
    transpose_sE<<<(int)((E + 2047) / 2048), 256, 0, stream>>>(sE, sT, E, Epad);
    edge_agg<<<(n + 3) / 4, 256, 0, stream>>>(rs, dstA, sT, Vb, Out, n);
}

// Round 20
// 419.479 us; speedup vs baseline: 1.1625x; 1.0151x over previous
//
#include <hip/hip_runtime.h>
#include <hip/hip_fp16.h>

typedef _Float16 f16;
typedef _Float16 f16x2 __attribute__((ext_vector_type(2)));
typedef _Float16 f16x4v __attribute__((ext_vector_type(4)));
typedef _Float16 f16x8 __attribute__((ext_vector_type(8)));
typedef float f32x4 __attribute__((ext_vector_type(4)));

// Combined projection: rows 0..511 = Wq (8 heads x 64), 512..1023 = Wk,
// 1024..1055 = Ww (V), 1056..1311 = Wb (output). Padded to 1408 rows (128-mult).
#define WC_ROWS 1312
#define WC_PAD 1408

// ---------------- prep: combined weight matrix (f16) + bias (f32) ----------------
__global__ void prep_weights(const float* __restrict__ Wq, const float* __restrict__ bq,
                             const float* __restrict__ Wk, const float* __restrict__ bk,
                             const float* __restrict__ Ww, const float* __restrict__ bw,
                             const float* __restrict__ Wb, const float* __restrict__ bb,
                             f16* __restrict__ Wc, float* __restrict__ bias) {
    int id = blockIdx.x * 256 + threadIdx.x;   // WC_PAD*256 threads
    int j = id >> 8, k = id & 255;
    if (j >= WC_PAD) return;
    float v;
    if (j < 512)       v = Wq[j*256 + k];          // Wq flat [8,64,256]: row h*64+d == j
    else if (j < 1024) v = Wk[(j-512)*256 + k];
    else if (j < 1056) v = Ww[(j-1024)*256 + k];
    else if (j < 1312) v = Wb[(j-1056)*256 + k];
    else               v = 0.f;
    Wc[j*256 + k] = (f16)v;
    if (k == 0) {
        float b;
        if (j < 512)       b = bq[j];
        else if (j < 1024) b = bk[j-512];
        else if (j < 1056) b = bw[j-1024];
        else if (j < 1312) b = bb[j-1056];
        else               b = 0.f;
        bias[j] = b;
    }
}

// ---------------- prep: features fp32 -> f16, zero-pad rows >= n ----------------
__global__ void conv_feat(const float* __restrict__ F, f16* __restrict__ Fh,
                          int n, long total) {
    long id = (long)blockIdx.x * 256 + threadIdx.x;
    long base = id * 4;
    if (base >= total) return;
    long row = base >> 8;
    float4 v = make_float4(0.f, 0.f, 0.f, 0.f);
    if (row < n) v = *(const float4*)(F + base);
    f16x4v o = { (f16)v.x, (f16)v.y, (f16)v.z, (f16)v.w };
    *(f16x4v*)(Fh + base) = o;
}

// ---------------- prep: CSR row starts (edges sorted by src; every row non-empty) --
__global__ void build_rows(const int* __restrict__ src, int E, int n, int* __restrict__ rs) {
    int e = blockIdx.x * 256 + threadIdx.x;
    if (e == 0) rs[n] = E;
    if (e < E) {
        if (e == 0 || src[e] != src[e-1]) rs[src[e]] = e;
    }
}

// ---------------- fused projection GEMM: m97-structure, SAFE barriers --------------
// global_load_lds(16B) staging + double-buffered LDS, ONE __syncthreads per K-step:
//   sync (tile-k loads landed + prior reads of buf^1 drained)
//   -> STAGE(k+1 into buf^1)   [loads in flight DURING the MFMA compute below]
//   -> ds_read + MFMA on buf k
// __syncthreads drains vmcnt/lgkmcnt before the barrier (compiler-guaranteed) —
// unlike r9's raw s_barrier + counted vmcnt, no stage can cross a barrier (the
// r10/r12 race). LDS layout linear (gload requirement); bank swizzle via
// pre-XORed per-lane GLOBAL source chunk (r9's refcheck-passed mapping).
__device__ __forceinline__ int frow(int r) { return (r & 3) ^ ((r >> 2) & 3); }

__device__ __forceinline__ void gload16(const f16* g, f16* l) {
    __builtin_amdgcn_global_load_lds(
        (const __attribute__((address_space(1))) void*)g,
        (__attribute__((address_space(3))) void*)l, 16, 0, 0);
}

__launch_bounds__(256)
__global__ void gemm_fused(const f16* __restrict__ A, const f16* __restrict__ Wc,
                           const float* __restrict__ bias,
                           f16* __restrict__ Qb, f16* __restrict__ Kb, f16* __restrict__ Vb,
                           float* __restrict__ Out, int n) {
    __shared__ uint4 As4[2][512];   // 128 rows x 32 k (f16), double-buffered = 16KB
    __shared__ uint4 Bs4[2][512];   // 128 rows x 32 k, double-buffered = 16KB
    int t = threadIdx.x;
    int lane = t & 63, w = t >> 6;
    int wm = w >> 1, wn = w & 1;
    long m0 = (long)blockIdx.y * 128;
    int n0 = blockIdx.x * 128;

    f32x4 acc[4][4];
    #pragma unroll
    for (int i = 0; i < 4; i++)
        #pragma unroll
        for (int j = 0; j < 4; j++)
            acc[i][j] = (f32x4){0.f, 0.f, 0.f, 0.f};

    int lrow = t >> 2, lc = t & 3;
    int cs = lc ^ frow(lrow);                 // pre-swizzled source chunk
    const f16* Ag0 = A + (m0 + lrow) * 256 + cs * 8;
    const f16* Ag1 = A + (m0 + 64 + lrow) * 256 + cs * 8;
    const f16* Bg0 = Wc + (long)(n0 + lrow) * 256 + cs * 8;
    const f16* Bg1 = Wc + (long)(n0 + 64 + lrow) * 256 + cs * 8;
    // wave-uniform LDS bases (hardware adds lane*16): slots t and 256+t
    f16* ldsA0 = (f16*)&As4[0][w * 64];
    f16* ldsA1 = (f16*)&As4[0][256 + w * 64];
    f16* ldsB0 = (f16*)&Bs4[0][w * 64];
    f16* ldsB1 = (f16*)&Bs4[0][256 + w * 64];

    int csw = (lane >> 4) ^ (lane & 3) ^ ((lane >> 2) & 3);
    int arow = wm * 64 + (lane & 15);
    int brow = wn * 64 + (lane & 15);

    #define STAGE(kt, b)  do {                              \
        int ko = (kt) * 32, bo = (b) * 512 * 8;             \
        gload16(Ag0 + ko, ldsA0 + bo);                      \
        gload16(Ag1 + ko, ldsA1 + bo);                      \
        gload16(Bg0 + ko, ldsB0 + bo);                      \
        gload16(Bg1 + ko, ldsB1 + bo);                      \
    } while (0)

    STAGE(0, 0);
    for (int kt = 0; kt < 8; ++kt) {
        int b = kt & 1;
        __syncthreads();               // tile-kt loads landed; buf b^1 reads drained
        if (kt < 7) STAGE(kt + 1, b ^ 1);   // in flight during the MFMAs below
        f16x8 af[4], bf[4];
        const f16x8* Ap = (const f16x8*)As4[b];
        const f16x8* Bp = (const f16x8*)Bs4[b];
        #pragma unroll
        for (int i = 0; i < 4; i++) af[i] = Ap[(arow + i * 16) * 4 + csw];
        #pragma unroll
        for (int j = 0; j < 4; j++) bf[j] = Bp[(brow + j * 16) * 4 + csw];
        #pragma unroll
        for (int i = 0; i < 4; i++)
            #pragma unroll
            for (int j = 0; j < 4; j++)
                acc[i][j] = __builtin_amdgcn_mfma_f32_16x16x32_f16(af[i], bf[j], acc[i][j], 0, 0, 0);
    }
    #undef STAGE

    // epilogue: C row = (lane>>4)*4 + reg (M), col = lane&15 (N)  [m89-verified]
    #pragma unroll
    for (int i = 0; i < 4; i++) {
        long gmb = m0 + wm * 64 + i * 16 + (lane >> 4) * 4;
        #pragma unroll
        for (int j = 0; j < 4; j++) {
            int gn = n0 + wn * 64 + j * 16 + (lane & 15);
            float bv = bias[gn];
            #pragma unroll
            for (int r = 0; r < 4; r++) {
                long gm = gmb + r;
                if (gm >= n) continue;
                float v = acc[i][j][r] + bv;
                if (gn < 512)       Qb[gm * 512 + gn] = (f16)v;
                else if (gn < 1024) Kb[gm * 512 + (gn - 512)] = (f16)v;
                else if (gn < 1056) Vb[gm * 32 + (gn - 1024)] = (f16)v;
                else if (gn < 1312) Out[gm * 256 + (gn - 1056)] = v;
                // gn in [1312,1408): padding, no write
            }
        }
    }
}

// ---------------- f16x2 dot helper ----------------
__device__ __forceinline__ float fd2(unsigned a, unsigned b, float c) {
#if defined(__has_builtin)
#if __has_builtin(__builtin_amdgcn_fdot2)
    return __builtin_amdgcn_fdot2(__builtin_bit_cast(f16x2, a), __builtin_bit_cast(f16x2, b), c, false);
#else
    f16x2 x = __builtin_bit_cast(f16x2, a), y = __builtin_bit_cast(f16x2, b);
    return c + (float)x[0] * (float)y[0] + (float)x[1] * (float)y[1];
#endif
#else
    f16x2 x = __builtin_bit_cast(f16x2, a), y = __builtin_bit_cast(f16x2, b);
    return c + (float)x[0] * (float)y[0] + (float)x[1] * (float)y[1];
#endif
}

// ---------------- phase A v5 (r16/r19-proven): chunk-lane coalesced, 4 edges/thread
// Lanes j=0..7 read one 128B K line in ONE instruction; 4 edges/thread; h = bid&7
// head-phasing (per-XCD K working set 6.4MB); packed f16x2 group reduce.
// 235us @ ~90% of the measured miss wall — local optimum (pin refuted 2x, fp8-K
// fails the error budget by arithmetic).
__launch_bounds__(256)
__global__ void edge_scores(const int* __restrict__ srcA, const int* __restrict__ dstA,
                            const f16* __restrict__ Qb, const f16* __restrict__ Kb,
                            f16* __restrict__ sE, int E, int Epad) {
    int bid = blockIdx.x;
    int h = bid & 7;                          // head = XCD (round-robin dispatch)
    int j = threadIdx.x & 7;                  // 16B chunk within the head's 128B line
    int g = threadIdx.x >> 3;                 // edge group 0..31
    int e0 = (bid >> 3) * 128 + g;            // edges e0 + 32*u, u=0..3
    int s[4], d[4];
    #pragma unroll
    for (int u = 0; u < 4; u++) {
        int e = e0 + 32 * u;
        bool ok = e < E;
        s[u] = ok ? srcA[e] : 0;
        d[u] = ok ? dstA[e] : 0;
    }
    uint4 kv[4], qv[4];
    #pragma unroll
    for (int u = 0; u < 4; u++)               // 4 gather lines issued back-to-back
        kv[u] = *(const uint4*)(Kb + (size_t)d[u] * 512 + h * 64 + j * 8);
    #pragma unroll
    for (int u = 0; u < 4; u++)               // 4 Q chunks (L1/L2-hot)
        qv[u] = *(const uint4*)(Qb + (size_t)s[u] * 512 + h * 64 + j * 8);
    float aa[4];
    #pragma unroll
    for (int u = 0; u < 4; u++) {
        float a = 0.f;
        a = fd2(qv[u].x, kv[u].x, a);
        a = fd2(qv[u].y, kv[u].y, a);
        a = fd2(qv[u].z, kv[u].z, a);
        a = fd2(qv[u].w, kv[u].w, a);
        aa[u] = a;
    }
    // packed 8-lane-group reduction: 2 regs carry 4 edges' partials
    f16x2 p01, p23;
    p01[0] = (f16)aa[0]; p01[1] = (f16)aa[1];
    p23[0] = (f16)aa[2]; p23[1] = (f16)aa[3];
    unsigned u01 = __builtin_bit_cast(unsigned, p01);
    unsigned u23 = __builtin_bit_cast(unsigned, p23);
    #pragma unroll
    for (int off = 1; off < 8; off <<= 1) {
        unsigned v01 = __shfl_xor(u01, off);
        unsigned v23 = __shfl_xor(u23, off);
        f16x2 r01 = __builtin_bit_cast(f16x2, u01) + __builtin_bit_cast(f16x2, v01);
        f16x2 r23 = __builtin_bit_cast(f16x2, u23) + __builtin_bit_cast(f16x2, v23);
        u01 = __builtin_bit_cast(unsigned, r01);
        u23 = __builtin_bit_cast(unsigned, r23);
    }
    if (j == 0) {
        f16x2 r01 = __builtin_bit_cast(f16x2, u01);
        f16x2 r23 = __builtin_bit_cast(f16x2, u23);
        size_t bo = (size_t)h * Epad;
        if (e0 < E)      sE[bo + e0]      = r01[0];
        if (e0+32 < E)   sE[bo + e0+32]   = r01[1];
        if (e0+64 < E)   sE[bo + e0+64]   = r23[0];
        if (e0+96 < E)   sE[bo + e0+96]   = r23[1];
    }
}

// ---------------- transpose: sE [h][Epad] -> sT [e][8] -----------------------------
__launch_bounds__(256)
__global__ void transpose_sE(const f16* __restrict__ sE, f16* __restrict__ sT,
                             int E, int Epad) {
    long e8 = (long)blockIdx.x * 2048 + (long)threadIdx.x * 8;   // this thread's 8 edges
    if (e8 >= E) return;
    f16x8 rowv[8];
    #pragma unroll
    for (int h = 0; h < 8; h++)
        rowv[h] = *(const f16x8*)(sE + (size_t)h * Epad + e8);   // 8 edges of head h
    #pragma unroll
    for (int u = 0; u < 8; u++) {
        long e = e8 + u;
        if (e < E) {
            f16x8 o;
            #pragma unroll
            for (int h = 0; h < 8; h++) o[h] = rowv[h][u];
            *(f16x8*)(sT + (size_t)e * 8) = o;
        }
    }
}

// ---------------- phase B v4 (r19-proven): single-pass online softmax --------------
__launch_bounds__(256)
__global__ void edge_agg(const int* __restrict__ rs, const int* __restrict__ dstA,
                         const f16* __restrict__ sT, const f16* __restrict__ Vb,
                         float* __restrict__ Out, int n) {
    __shared__ __align__(16) f16 P_lds[4][16][64];
    __shared__ int dS[4][64];
    int w = threadIdx.x >> 6, lane = threadIdx.x & 63;
    int row = blockIdx.x * 4 + w;
    if (row >= n) return;
    int e0 = rs[row], deg = rs[row + 1] - e0;
    {   // zero A-frag rows 8..15 (read by MFMA, results discarded; avoid NaN garbage)
        f16x8 z = {};
        *(f16x8*)&P_lds[w][8 + (lane >> 3)][(lane & 7) * 8] = z;
    }
    asm volatile("" ::: "memory");
    float m[8];
    #pragma unroll
    for (int h = 0; h < 8; h++) m[h] = -1e30f;
    f32x4 acc0 = {}, acc1 = {}, accl = {};
    int ec0 = (lane >> 4) * 8, h_a = lane & 15, hsel = (lane >> 4) & 1;
    f16x8 ones;
    #pragma unroll
    for (int j = 0; j < 8; j++) ones[j] = (f16)1.f;

    for (int base = 0; base < deg; base += 64) {
        int nE = deg - base; if (nE > 64) nE = 64;
        bool act = lane < nE;
        int ee = e0 + base + (act ? lane : 0);
        dS[w][lane] = dstA[ee];
        f16x8 s8 = *(const f16x8*)(sT + (size_t)ee * 8);   // all 8 heads, one load
        // packed tile-max: 4x f16x2 butterflies (f16 max is exact)
        f16x2 mx[4];
        #pragma unroll
        for (int p = 0; p < 4; p++) {
            f16x2 v;
            v[0] = s8[2*p]; v[1] = s8[2*p + 1];
            if (!act) { v[0] = (f16)(-65504.f); v[1] = (f16)(-65504.f); }
            mx[p] = v;
        }
        #pragma unroll
        for (int off = 1; off < 64; off <<= 1) {
            #pragma unroll
            for (int p = 0; p < 4; p++) {
                unsigned o = __shfl_xor(__builtin_bit_cast(unsigned, mx[p]), off);
                mx[p] = __builtin_elementwise_max(mx[p], __builtin_bit_cast(f16x2, o));
            }
        }
        float sc[8];
        #pragma unroll
        for (int h = 0; h < 8; h++) {
            float tv = (float)mx[h >> 1][h & 1];
            float nm = fmaxf(m[h], tv);
            sc[h] = __expf(m[h] - nm);
            float sv = act ? (float)s8[h] : -1e30f;
            float p = act ? __expf(sv - nm) : 0.f;
            P_lds[w][h][lane ^ (h << 3)] = (f16)p;
            m[h] = nm;
        }
        #pragma unroll
        for (int r = 0; r < 4; r++) {   // rescale accs (head = hsel*4 + r)
            float f = hsel ? sc[r + 4] : sc[r];
            acc0[r] *= f;
            acc1[r] *= f;
            accl[r] *= f;
        }
        asm volatile("" ::: "memory");   // LDS writes ordered before the punned reads
        // A-frags: P[h][k], k = ks*32 + ec0 + j (XOR-decoded contiguous b128)
        f16x8 a0 = *(const f16x8*)&P_lds[w][h_a][(ec0)      ^ ((h_a & 7) << 3)];
        f16x8 a1 = *(const f16x8*)&P_lds[w][h_a][(32 + ec0) ^ ((h_a & 7) << 3)];
        // B-frags: V[e][dim], dim = nh*16 + (lane&15)
        f16x8 bf0a, bf0b, bf1a, bf1b;
        #pragma unroll
        for (int j = 0; j < 8; j++) {
            int dd0 = dS[w][ec0 + j];
            int dd1 = dS[w][32 + ec0 + j];
            const f16* vp0 = Vb + (size_t)dd0 * 32 + (lane & 15);
            const f16* vp1 = Vb + (size_t)dd1 * 32 + (lane & 15);
            bf0a[j] = vp0[0];  bf0b[j] = vp0[16];
            bf1a[j] = vp1[0];  bf1b[j] = vp1[16];
        }
        asm volatile("" ::: "memory");   // reads complete before next tile's writes
        acc0 = __builtin_amdgcn_mfma_f32_16x16x32_f16(a0, bf0a, acc0, 0, 0, 0);
        acc0 = __builtin_amdgcn_mfma_f32_16x16x32_f16(a1, bf1a, acc0, 0, 0, 0);
        acc1 = __builtin_amdgcn_mfma_f32_16x16x32_f16(a0, bf0b, acc1, 0, 0, 0);
        acc1 = __builtin_amdgcn_mfma_f32_16x16x32_f16(a1, bf1b, acc1, 0, 0, 0);
        accl = __builtin_amdgcn_mfma_f32_16x16x32_f16(a0, ones, accl, 0, 0, 0);
        accl = __builtin_amdgcn_mfma_f32_16x16x32_f16(a1, ones, accl, 0, 0, 0);
    }
    // epilogue: D row = hsel*4 + r = head, col = lane&15; out dim = h*32 + nh*16 + col
    if (lane < 32) {
        float* op = Out + (size_t)row * 256 + (lane & 15);
        #pragma unroll
        for (int r = 0; r < 4; r++) {
            int h = hsel * 4 + r;
            float inv = 1.f / accl[r];
            op[h * 32]      += acc0[r] * inv;
            op[h * 32 + 16] += acc1[r] * inv;
        }
    }
}

// ---------------- launch ----------------
extern "C" void kernel_launch(void* const* d_in, const int* in_sizes, int n_in,
                              void* d_out, int out_size, void* d_ws, size_t ws_size,
                              hipStream_t stream) {
    const float* F  = (const float*)d_in[0];
    const int*   ei = (const int*)d_in[1];
    const float* Wq = (const float*)d_in[2];
    const float* bq = (const float*)d_in[3];
    const float* Wk = (const float*)d_in[4];
    const float* bk = (const float*)d_in[5];
    const float* Ww = (const float*)d_in[6];
    const float* bw = (const float*)d_in[7];
    const float* Wb = (const float*)d_in[8];
    const float* bb = (const float*)d_in[9];
    int n = in_sizes[0] / 256;       // 50000
    int E = in_sizes[1] / 2;
    const int* srcA = ei;
    const int* dstA = ei + E;
    int n_pad = (n + 127) & ~127;
    int Epad = (E + 63) & ~63;

    // workspace carve-out (~133 MB); Fh and sE alias (Fh dead after gemm_fused);
    // sT aliases Qb (dead after edge_scores)
    char* wp = (char*)d_ws;
    auto alloc = [&](size_t bytes) { void* p = wp; wp += (bytes + 255) & ~255ull; return p; };
    size_t fhB = (size_t)n_pad * 256 * 2;
    size_t seB = (size_t)Epad * 8 * 2;
    void*  reg0 = alloc(fhB > seB ? fhB : seB);
    f16*   Fh   = (f16*)reg0;
    f16*   sE   = (f16*)reg0;
    f16*   Wc   = (f16*)alloc((size_t)WC_PAD * 256 * 2);
    float* bias = (float*)alloc((size_t)WC_PAD * 4);
    f16*   Qb   = (f16*)alloc((size_t)n * 512 * 2);
    f16*   Kb   = (f16*)alloc((size_t)n * 512 * 2);
    f16*   Vb   = (f16*)alloc((size_t)n * 32 * 2);
    int*   rs   = (int*)alloc((size_t)(n + 1) * 4);
    float* Out  = (float*)d_out;
    f16*   sT   = Qb;                // alias: Qb (51MB) >= sT (26MB), dead after scores

    prep_weights<<<WC_PAD, 256, 0, stream>>>(Wq, bq, Wk, bk, Ww, bw, Wb, bb, Wc, bias);
    long totalF = (long)n_pad * 256;
    conv_feat<<<(int)((totalF / 4 + 255) / 256), 256, 0, stream>>>(F, Fh, n, totalF);
    build_rows<<<(E + 255) / 256, 256, 0, stream>>>(srcA, E, n, rs);
    dim3 g(WC_PAD / 128, n_pad / 128);   // N fastest: A-panel L2-reuse, B L2-resident
    gemm_fused<<<g, 256, 0, stream>>>(Fh, Wc, bias, Qb, Kb, Vb, Out, n);
    int wgph = (E + 127) / 128;          // 128 edges per block per head
    edge_scores<<<8 * wgph, 256, 0, stream>>>(srcA, dstA, Qb, Kb, sE, E, Epad);
    transpose_sE<<<(int)((E + 2047) / 2048), 256, 0, stream>>>(sE, sT, E, Epad);
    edge_agg<<<(n + 3) / 4, 256, 0, stream>>>(rs, dstA, sT, Vb, Out, n);
}